// Round 3
// baseline (169.084 us; speedup 1.0000x reference)
//
#include <hip/hip_runtime.h>
#include <cstdint>
#include <cstddef>

#define NB 16
#define NC 256
#define NN 4096
#define ND 256

typedef unsigned short u16;
typedef unsigned int u32;

typedef __attribute__((ext_vector_type(8))) short short8;
typedef __attribute__((ext_vector_type(4))) float f32x4;

__device__ __forceinline__ u16 f2bf(float f) {
  union { float f; u32 u; } v; v.f = f;
  u32 r = v.u + 0x7FFFu + ((v.u >> 16) & 1u);
  return (u16)(r >> 16);
}
__device__ __forceinline__ float bf2f(u16 h) {
  union { u32 u; float f; } v; v.u = ((u32)h) << 16; return v.f;
}

// ---------------------------------------------------------------------------
// Kernel 0: blocks 0..271 zero q+xs; blocks 272..335 cast Wv -> bf16
// ---------------------------------------------------------------------------
__global__ __launch_bounds__(256) void k_init(const float* __restrict__ W,
                                              float* __restrict__ q,
                                              float* __restrict__ xs,
                                              u16* __restrict__ wvb) {
  const int blk = blockIdx.x, t = threadIdx.x;
  if (blk < 272) {
    const int i = blk * 256 + t;   // 0..69631
    if (i < NB * NN) q[i] = 0.f;
    else xs[i - NB * NN] = 0.f;
  } else {
    const int i = ((blk - 272) * 256 + t) * 4;
    const float4 v = *(const float4*)(W + (size_t)(1 + ND) * NC + i);
    ushort4 o;
    o.x = f2bf(v.x); o.y = f2bf(v.y); o.z = f2bf(v.z); o.w = f2bf(v.w);
    *(ushort4*)(wvb + i) = o;
  }
}

// ---------------------------------------------------------------------------
// Kernel 1: cast x (fp32 [b][c][n]) -> xbT (bf16 [b][n][c]) via LDS transpose,
// fused with partial q[b][n] += sum_c W[0][c]*x[b][c][n].
// ---------------------------------------------------------------------------
__global__ __launch_bounds__(256) void k_cast_transpose_q(const float* __restrict__ x,
                                                          const float* __restrict__ W,
                                                          u16* __restrict__ xbT,
                                                          float* __restrict__ q) {
  __shared__ __align__(16) u16 tile[64 * 68];
  __shared__ float qred[16 * 64];
  const int t = threadIdx.x;
  const int b = blockIdx.z, c0 = blockIdx.y * 64, n0 = blockIdx.x * 64;
  const float* xb = x + (size_t)(b * NC + c0) * NN + n0;
  const int nl = (t & 15) * 4;
  float qacc[4] = {0.f, 0.f, 0.f, 0.f};
#pragma unroll
  for (int i = 0; i < 4; ++i) {
    int cl = (t >> 4) + i * 16;   // 0..63
    float4 v = *(const float4*)(xb + (size_t)cl * NN + nl);
    const float wq = W[c0 + cl];
    qacc[0] += wq * v.x; qacc[1] += wq * v.y;
    qacc[2] += wq * v.z; qacc[3] += wq * v.w;
    tile[(nl + 0) * 68 + cl] = f2bf(v.x);
    tile[(nl + 1) * 68 + cl] = f2bf(v.y);
    tile[(nl + 2) * 68 + cl] = f2bf(v.z);
    tile[(nl + 3) * 68 + cl] = f2bf(v.w);
  }
#pragma unroll
  for (int j = 0; j < 4; ++j) qred[(t >> 4) * 64 + nl + j] = qacc[j];
  __syncthreads();
  u16* ob = xbT + (size_t)(b * NN + n0) * NC + c0;
#pragma unroll
  for (int i = 0; i < 4; ++i) {
    int e = t + i * 256;
    int rn = e >> 4;            // 0..63
    int rc = (e & 15) * 4;      // 0..60
    ushort4 pv = *(const ushort4*)&tile[rn * 68 + rc];
    *(ushort4*)(ob + (size_t)rn * NC + rc) = pv;
  }
  if (t < 64) {
    float s = 0.f;
#pragma unroll
    for (int k = 0; k < 16; ++k) s += qred[k * 64 + t];
    atomicAdd(&q[b * NN + n0 + t], s);
  }
}

// ---------------------------------------------------------------------------
// Kernel 2: softmax over n (block=1024, float4 per thread, shuffle reduce)
// ---------------------------------------------------------------------------
__global__ __launch_bounds__(1024) void k_softmax(const float* __restrict__ q,
                                                  float* __restrict__ s) {
  __shared__ float redm[16];
  __shared__ float redz[16];
  const int b = blockIdx.x, t = threadIdx.x;
  const int wave = t >> 6, lane = t & 63;
  float4 v = *(const float4*)(q + (size_t)b * NN + t * 4);
  float m = fmaxf(fmaxf(v.x, v.y), fmaxf(v.z, v.w));
#pragma unroll
  for (int off = 32; off > 0; off >>= 1) m = fmaxf(m, __shfl_down(m, off));
  if (lane == 0) redm[wave] = m;
  __syncthreads();
  float M = redm[0];
#pragma unroll
  for (int k = 1; k < 16; ++k) M = fmaxf(M, redm[k]);
  float4 e;
  e.x = __expf(v.x - M); e.y = __expf(v.y - M);
  e.z = __expf(v.z - M); e.w = __expf(v.w - M);
  float sum = e.x + e.y + e.z + e.w;
#pragma unroll
  for (int off = 32; off > 0; off >>= 1) sum += __shfl_down(sum, off);
  if (lane == 0) redz[wave] = sum;
  __syncthreads();
  float Z = 0.f;
#pragma unroll
  for (int k = 0; k < 16; ++k) Z += redz[k];
  const float inv = 1.f / Z;
  e.x *= inv; e.y *= inv; e.z *= inv; e.w *= inv;
  *(float4*)(s + (size_t)b * NN + t * 4) = e;
}

// ---------------------------------------------------------------------------
// Kernel 3: xs[b][c] += sum_n xbT[b][n][c]*s[b][n].  ushort4 loads (8B/lane),
// 4 waves each own 32 of the block's 128 n; LDS combine; 1 atomicAdd/(b,c).
// ---------------------------------------------------------------------------
__global__ __launch_bounds__(256) void k_xs(const u16* __restrict__ xbT,
                                            const float* __restrict__ s,
                                            float* __restrict__ xs) {
  __shared__ float red[4 * 256];
  const int t = threadIdx.x;
  const int b = blockIdx.y, n0 = blockIdx.x * 128;
  const int w = t >> 6, c4 = (t & 63) * 4;
  const u16* xp = xbT + ((size_t)(b * NN + n0 + w * 32)) * NC + c4;
  const float* sp = s + b * NN + n0 + w * 32;
  float a0 = 0.f, a1 = 0.f, a2 = 0.f, a3 = 0.f;
#pragma unroll 8
  for (int j = 0; j < 32; ++j) {
    ushort4 v = *(const ushort4*)(xp + (size_t)j * NC);
    float sv = sp[j];
    a0 += bf2f(v.x) * sv; a1 += bf2f(v.y) * sv;
    a2 += bf2f(v.z) * sv; a3 += bf2f(v.w) * sv;
  }
  red[w * 256 + c4 + 0] = a0; red[w * 256 + c4 + 1] = a1;
  red[w * 256 + c4 + 2] = a2; red[w * 256 + c4 + 3] = a3;
  __syncthreads();
  float sum = red[t] + red[256 + t] + red[512 + t] + red[768 + t];
  atomicAdd(&xs[b * NC + t], sum);
}

// ---------------------------------------------------------------------------
// Kernel 4: ctx[b][d] = sum_c W[1+d][c] * xs[b][c]
// ---------------------------------------------------------------------------
__global__ __launch_bounds__(256) void k_ctx(const float* __restrict__ W,
                                             const float* __restrict__ xs,
                                             float* __restrict__ ctx) {
  __shared__ float sx[NC];
  const int b = blockIdx.x, d = threadIdx.x;
  sx[d] = xs[b * NC + d];
  __syncthreads();
  const float* wk = W + (size_t)(1 + d) * NC;
  float acc = 0.f;
#pragma unroll 4
  for (int c = 0; c < NC; ++c) acc += wk[c] * sx[c];
  ctx[b * NC + d] = acc;
}

// ---------------------------------------------------------------------------
// Kernel 5: out[b][d][n] = relu((Wv @ x)[d][n]) * ctx[b][d]
// LDS-FREE gemm: fragments loaded directly from global (wvb L2-resident,
// xbT L3-resident; per-wave the 4 quads cover 64 contiguous bytes per row ->
// full line utilization). Block = 64d x 256n, 4 waves side-by-side in n
// (B never duplicated in-block). Register double-buffered over 8 K-iters.
// No __syncthreads, no LDS, no bank conflicts, no barrier drain.
// ---------------------------------------------------------------------------
__global__ __launch_bounds__(256) void k_gemm(const u16* __restrict__ xbT,
                                              const u16* __restrict__ wvb,
                                              const float* __restrict__ ctx,
                                              float* __restrict__ out) {
  const int t = threadIdx.x;
  const int b = blockIdx.z;
  const int d0 = blockIdx.y * 64;
  const int n0 = blockIdx.x * 256;
  const int lane = t & 63, w = t >> 6;
  const int wn = w * 64;
  const int quad = lane >> 4, l15 = lane & 15;

  const u16* pA = wvb + (size_t)(d0 + l15) * NC + quad * 8;
  const u16* pB = xbT + (size_t)(b * NN + n0 + wn + l15) * NC + quad * 8;

  f32x4 acc[4][4];
#pragma unroll
  for (int mi = 0; mi < 4; ++mi)
#pragma unroll
    for (int ni = 0; ni < 4; ++ni)
      acc[mi][ni] = (f32x4){0.f, 0.f, 0.f, 0.f};

  short8 af[2][4], bfr[2][4];
#pragma unroll
  for (int mi = 0; mi < 4; ++mi) af[0][mi] = *(const short8*)(pA + (size_t)mi * 16 * NC);
#pragma unroll
  for (int ni = 0; ni < 4; ++ni) bfr[0][ni] = *(const short8*)(pB + (size_t)ni * 16 * NC);

#pragma unroll
  for (int kt = 1; kt < 8; ++kt) {
    const int cur = (kt - 1) & 1, nxt = kt & 1;
    const int kk = kt * 32;
#pragma unroll
    for (int mi = 0; mi < 4; ++mi)
      af[nxt][mi] = *(const short8*)(pA + (size_t)mi * 16 * NC + kk);
#pragma unroll
    for (int ni = 0; ni < 4; ++ni)
      bfr[nxt][ni] = *(const short8*)(pB + (size_t)ni * 16 * NC + kk);
#pragma unroll
    for (int mi = 0; mi < 4; ++mi)
#pragma unroll
      for (int ni = 0; ni < 4; ++ni)
        acc[mi][ni] = __builtin_amdgcn_mfma_f32_16x16x32_bf16(af[cur][mi], bfr[cur][ni],
                                                              acc[mi][ni], 0, 0, 0);
  }
#pragma unroll
  for (int mi = 0; mi < 4; ++mi)
#pragma unroll
    for (int ni = 0; ni < 4; ++ni)
      acc[mi][ni] = __builtin_amdgcn_mfma_f32_16x16x32_bf16(af[1][mi], bfr[1][ni],
                                                            acc[mi][ni], 0, 0, 0);

#pragma unroll
  for (int mi = 0; mi < 4; ++mi) {
#pragma unroll
    for (int r = 0; r < 4; ++r) {
      const int d = d0 + mi * 16 + quad * 4 + r;
      const float cx = ctx[b * NC + d];
      float* op = out + (size_t)(b * NC + d) * NN + n0 + wn + l15;
#pragma unroll
      for (int ni = 0; ni < 4; ++ni) {
        float v = acc[mi][ni][r];
        op[ni * 16] = fmaxf(v, 0.f) * cx;
      }
    }
  }
}

// ---------------------------------------------------------------------------
extern "C" void kernel_launch(void* const* d_in, const int* in_sizes, int n_in,
                              void* d_out, int out_size, void* d_ws, size_t ws_size,
                              hipStream_t stream) {
  const float* x = (const float*)d_in[0];
  const float* W = (const float*)d_in[1];
  float* out = (float*)d_out;

  char* ws = (char*)d_ws;
  u16* xbT   = (u16*)ws;                                  // 33,554,432 B
  float* q   = (float*)(ws + 33554432);                   //    262,144 B
  float* s   = (float*)(ws + 33554432 + 262144);          //    262,144 B
  float* xs  = (float*)(ws + 33554432 + 524288);          //     16,384 B
  float* ctx = (float*)(ws + 33554432 + 540672);          //     16,384 B
  u16* wvb   = (u16*)(ws + 33554432 + 557056);            //    131,072 B

  k_init<<<336, 256, 0, stream>>>(W, q, xs, wvb);
  k_cast_transpose_q<<<dim3(64, 4, 16), 256, 0, stream>>>(x, W, xbT, q);
  k_softmax<<<16, 1024, 0, stream>>>(q, s);
  k_xs<<<dim3(32, 16), 256, 0, stream>>>(xbT, s, xs);
  k_ctx<<<16, 256, 0, stream>>>(W, xs, ctx);
  k_gemm<<<dim3(16, 4, 16), 256, 0, stream>>>(xbT, wvb, ctx, out);
}

// Round 4
// 161.873 us; speedup vs baseline: 1.0445x; 1.0445x over previous
//
#include <hip/hip_runtime.h>
#include <cstdint>
#include <cstddef>

#define NB 16
#define NC 256
#define NN 4096
#define ND 256

typedef unsigned short u16;
typedef unsigned int u32;

typedef __attribute__((ext_vector_type(8))) short short8;
typedef __attribute__((ext_vector_type(4))) float f32x4;

__device__ __forceinline__ u16 f2bf(float f) {
  union { float f; u32 u; } v; v.f = f;
  u32 r = v.u + 0x7FFFu + ((v.u >> 16) & 1u);
  return (u16)(r >> 16);
}
__device__ __forceinline__ float bf2f(u16 h) {
  union { u32 u; float f; } v; v.u = ((u32)h) << 16; return v.f;
}

// ---------------------------------------------------------------------------
// Kernel 0: blocks 0..271 zero q+xs; blocks 272..335 cast Wv -> bf16
// ---------------------------------------------------------------------------
__global__ __launch_bounds__(256) void k_init(const float* __restrict__ W,
                                              float* __restrict__ q,
                                              float* __restrict__ xs,
                                              u16* __restrict__ wvb) {
  const int blk = blockIdx.x, t = threadIdx.x;
  if (blk < 272) {
    const int i = blk * 256 + t;
    if (i < NB * NN) q[i] = 0.f;
    else xs[i - NB * NN] = 0.f;
  } else {
    const int i = ((blk - 272) * 256 + t) * 4;
    const float4 v = *(const float4*)(W + (size_t)(1 + ND) * NC + i);
    ushort4 o;
    o.x = f2bf(v.x); o.y = f2bf(v.y); o.z = f2bf(v.z); o.w = f2bf(v.w);
    *(ushort4*)(wvb + i) = o;
  }
}

// ---------------------------------------------------------------------------
// Kernel 1: cast x (fp32 [b][c][n]) -> xbT (bf16 [b][n][c]) via LDS transpose,
// fused with partial q[b][n] += sum_c W[0][c]*x[b][c][n].
// ---------------------------------------------------------------------------
__global__ __launch_bounds__(256) void k_cast_transpose_q(const float* __restrict__ x,
                                                          const float* __restrict__ W,
                                                          u16* __restrict__ xbT,
                                                          float* __restrict__ q) {
  __shared__ __align__(16) u16 tile[64 * 68];
  __shared__ float qred[16 * 64];
  const int t = threadIdx.x;
  const int b = blockIdx.z, c0 = blockIdx.y * 64, n0 = blockIdx.x * 64;
  const float* xb = x + (size_t)(b * NC + c0) * NN + n0;
  const int nl = (t & 15) * 4;
  float qacc[4] = {0.f, 0.f, 0.f, 0.f};
#pragma unroll
  for (int i = 0; i < 4; ++i) {
    int cl = (t >> 4) + i * 16;
    float4 v = *(const float4*)(xb + (size_t)cl * NN + nl);
    const float wq = W[c0 + cl];
    qacc[0] += wq * v.x; qacc[1] += wq * v.y;
    qacc[2] += wq * v.z; qacc[3] += wq * v.w;
    tile[(nl + 0) * 68 + cl] = f2bf(v.x);
    tile[(nl + 1) * 68 + cl] = f2bf(v.y);
    tile[(nl + 2) * 68 + cl] = f2bf(v.z);
    tile[(nl + 3) * 68 + cl] = f2bf(v.w);
  }
#pragma unroll
  for (int j = 0; j < 4; ++j) qred[(t >> 4) * 64 + nl + j] = qacc[j];
  __syncthreads();
  u16* ob = xbT + (size_t)(b * NN + n0) * NC + c0;
#pragma unroll
  for (int i = 0; i < 4; ++i) {
    int e = t + i * 256;
    int rn = e >> 4;
    int rc = (e & 15) * 4;
    ushort4 pv = *(const ushort4*)&tile[rn * 68 + rc];
    *(ushort4*)(ob + (size_t)rn * NC + rc) = pv;
  }
  if (t < 64) {
    float s = 0.f;
#pragma unroll
    for (int k = 0; k < 16; ++k) s += qred[k * 64 + t];
    atomicAdd(&q[b * NN + n0 + t], s);
  }
}

// ---------------------------------------------------------------------------
// Kernel 2: softmax over n (block=1024, float4 per thread, shuffle reduce)
// ---------------------------------------------------------------------------
__global__ __launch_bounds__(1024) void k_softmax(const float* __restrict__ q,
                                                  float* __restrict__ s) {
  __shared__ float redm[16];
  __shared__ float redz[16];
  const int b = blockIdx.x, t = threadIdx.x;
  const int wave = t >> 6, lane = t & 63;
  float4 v = *(const float4*)(q + (size_t)b * NN + t * 4);
  float m = fmaxf(fmaxf(v.x, v.y), fmaxf(v.z, v.w));
#pragma unroll
  for (int off = 32; off > 0; off >>= 1) m = fmaxf(m, __shfl_down(m, off));
  if (lane == 0) redm[wave] = m;
  __syncthreads();
  float M = redm[0];
#pragma unroll
  for (int k = 1; k < 16; ++k) M = fmaxf(M, redm[k]);
  float4 e;
  e.x = __expf(v.x - M); e.y = __expf(v.y - M);
  e.z = __expf(v.z - M); e.w = __expf(v.w - M);
  float sum = e.x + e.y + e.z + e.w;
#pragma unroll
  for (int off = 32; off > 0; off >>= 1) sum += __shfl_down(sum, off);
  if (lane == 0) redz[wave] = sum;
  __syncthreads();
  float Z = 0.f;
#pragma unroll
  for (int k = 0; k < 16; ++k) Z += redz[k];
  const float inv = 1.f / Z;
  e.x *= inv; e.y *= inv; e.z *= inv; e.w *= inv;
  *(float4*)(s + (size_t)b * NN + t * 4) = e;
}

// ---------------------------------------------------------------------------
// Kernel 3: xs[b][c] += sum_n xbT[b][n][c]*s[b][n]
// ---------------------------------------------------------------------------
__global__ __launch_bounds__(256) void k_xs(const u16* __restrict__ xbT,
                                            const float* __restrict__ s,
                                            float* __restrict__ xs) {
  __shared__ float red[4 * 256];
  const int t = threadIdx.x;
  const int b = blockIdx.y, n0 = blockIdx.x * 128;
  const int w = t >> 6, c4 = (t & 63) * 4;
  const u16* xp = xbT + ((size_t)(b * NN + n0 + w * 32)) * NC + c4;
  const float* sp = s + b * NN + n0 + w * 32;
  float a0 = 0.f, a1 = 0.f, a2 = 0.f, a3 = 0.f;
#pragma unroll 8
  for (int j = 0; j < 32; ++j) {
    ushort4 v = *(const ushort4*)(xp + (size_t)j * NC);
    float sv = sp[j];
    a0 += bf2f(v.x) * sv; a1 += bf2f(v.y) * sv;
    a2 += bf2f(v.z) * sv; a3 += bf2f(v.w) * sv;
  }
  red[w * 256 + c4 + 0] = a0; red[w * 256 + c4 + 1] = a1;
  red[w * 256 + c4 + 2] = a2; red[w * 256 + c4 + 3] = a3;
  __syncthreads();
  float sum = red[t] + red[256 + t] + red[512 + t] + red[768 + t];
  atomicAdd(&xs[b * NC + t], sum);
}

// ---------------------------------------------------------------------------
// Kernel 4: out[b][d][n] = relu((Wv @ x)[d][n]) * ctx[b][d]
// 128x128 tile, BK=32, single-barrier double-buffered LDS pipeline with
// global_load_lds(16B). XOR swizzle: phys_chunk = chunk ^ (row&3) keeps
// ds_read_b128 at <=4-way. ctx fused: recomputed per block from W,xs (fp32)
// while the first stage flies.
// ---------------------------------------------------------------------------
#define BK 32

__global__ __launch_bounds__(256) void k_gemm(const u16* __restrict__ xbT,
                                              const u16* __restrict__ wvb,
                                              const float* __restrict__ W,
                                              const float* __restrict__ xs,
                                              float* __restrict__ out) {
  __shared__ __align__(16) u16 As[2][128 * BK];   // 2 x 8 KB
  __shared__ __align__(16) u16 Bs[2][128 * BK];   // 2 x 8 KB
  __shared__ float ctxred[256];
  const int t = threadIdx.x;
  const int b = blockIdx.z;
  const int d0 = blockIdx.y * 128;
  const int n0 = blockIdx.x * 128;
  const int lane = t & 63, w = t >> 6;
  const int wd = (w & 1) * 64, wn = (w >> 1) * 64;
  const int quad = lane >> 4, l15 = lane & 15;

  // staging map: thread t -> row (t>>2)(+64), phys chunk t&3,
  // logical chunk (t&3)^(row&3); LDS dest = t*16B (lane-linear).
  const int rstg = t >> 2;
  const int l8 = ((t & 3) ^ (rstg & 3)) * 8;
  const u16* gA = wvb + (size_t)(d0 + rstg) * NC + l8;
  const u16* gB = xbT + (size_t)(b * NN + n0 + rstg) * NC + l8;
  const int ldst = 8 * t;

#define STAGE(buf, kk)                                                          \
  do {                                                                          \
    _Pragma("unroll")                                                           \
    for (int i = 0; i < 2; ++i) {                                               \
      __builtin_amdgcn_global_load_lds(                                         \
          (const __attribute__((address_space(1))) u32*)(gA + (kk) + (size_t)(64 * i) * NC), \
          (__attribute__((address_space(3))) u32*)(As[buf] + 2048 * i + ldst), 16, 0, 0);    \
      __builtin_amdgcn_global_load_lds(                                         \
          (const __attribute__((address_space(1))) u32*)(gB + (kk) + (size_t)(64 * i) * NC), \
          (__attribute__((address_space(3))) u32*)(Bs[buf] + 2048 * i + ldst), 16, 0, 0);    \
    }                                                                           \
  } while (0)

  STAGE(0, 0);   // stage kt=0 while ctx prologue computes

  // fused ctx: thread t handles d_local=t>>1, half=t&1 (128 c each)
  {
    const int dl = t >> 1, half = t & 1;
    const float* wk = W + (size_t)(1 + d0 + dl) * NC + half * 128;
    const float* xp = xs + b * NC + half * 128;
    float a = 0.f;
#pragma unroll 8
    for (int j = 0; j < 128; ++j) a += wk[j] * xp[j];
    ctxred[t] = a;
  }

  f32x4 acc[4][4];
#pragma unroll
  for (int mi = 0; mi < 4; ++mi)
#pragma unroll
    for (int ni = 0; ni < 4; ++ni)
      acc[mi][ni] = (f32x4){0.f, 0.f, 0.f, 0.f};

  const int pq = (quad ^ (l15 & 3)) * 8;   // phys chunk offset for frag reads

#pragma unroll
  for (int kt = 0; kt < 8; ++kt) {
    const int buf = kt & 1;
    __syncthreads();           // drains loads for kt (issued last iter) + LDS reuse safety
    if (kt < 7) STAGE(buf ^ 1, (kt + 1) * BK);
    short8 af[4], bfr[4];
#pragma unroll
    for (int mi = 0; mi < 4; ++mi)
      af[mi] = *(const short8*)&As[buf][(wd + mi * 16 + l15) * BK + pq];
#pragma unroll
    for (int ni = 0; ni < 4; ++ni)
      bfr[ni] = *(const short8*)&Bs[buf][(wn + ni * 16 + l15) * BK + pq];
#pragma unroll
    for (int mi = 0; mi < 4; ++mi)
#pragma unroll
      for (int ni = 0; ni < 4; ++ni)
        acc[mi][ni] = __builtin_amdgcn_mfma_f32_16x16x32_bf16(af[mi], bfr[ni],
                                                              acc[mi][ni], 0, 0, 0);
  }

#pragma unroll
  for (int mi = 0; mi < 4; ++mi) {
#pragma unroll
    for (int r = 0; r < 4; ++r) {
      const int dl = wd + mi * 16 + quad * 4 + r;
      const float cx = ctxred[2 * dl] + ctxred[2 * dl + 1];
      float* op = out + (size_t)(b * NC + d0 + dl) * NN + n0 + wn + l15;
#pragma unroll
      for (int ni = 0; ni < 4; ++ni) {
        float v = acc[mi][ni][r];
        op[ni * 16] = fmaxf(v, 0.f) * cx;
      }
    }
  }
#undef STAGE
}

// ---------------------------------------------------------------------------
extern "C" void kernel_launch(void* const* d_in, const int* in_sizes, int n_in,
                              void* d_out, int out_size, void* d_ws, size_t ws_size,
                              hipStream_t stream) {
  const float* x = (const float*)d_in[0];
  const float* W = (const float*)d_in[1];
  float* out = (float*)d_out;

  char* ws = (char*)d_ws;
  u16* xbT   = (u16*)ws;                                  // 33,554,432 B
  float* q   = (float*)(ws + 33554432);
  float* s   = (float*)(ws + 33554432 + 262144);
  float* xs  = (float*)(ws + 33554432 + 524288);
  u16* wvb   = (u16*)(ws + 33554432 + 557056);

  k_init<<<336, 256, 0, stream>>>(W, q, xs, wvb);
  k_cast_transpose_q<<<dim3(64, 4, 16), 256, 0, stream>>>(x, W, xbT, q);
  k_softmax<<<16, 1024, 0, stream>>>(q, s);
  k_xs<<<dim3(32, 16), 256, 0, stream>>>(xbT, s, xs);
  k_gemm<<<dim3(32, 2, 16), 256, 0, stream>>>(xbT, wvb, W, xs, out);
}